// Round 3
// baseline (339.910 us; speedup 1.0000x reference)
//
#include <hip/hip_runtime.h>

#define NCLS 13
#define DIM  256
#define INV_T (1.0f/0.07f)

typedef short bf16x8 __attribute__((ext_vector_type(8)));
typedef float f32x4  __attribute__((ext_vector_type(4)));

__device__ __forceinline__ float bf2f(unsigned short u){
  union { unsigned u; float f; } v; v.u = ((unsigned)u) << 16; return v.f;
}
__device__ __forceinline__ unsigned short f2bf(float f){
  union { float f; unsigned u; } v; v.f = f;
  unsigned r = v.u + 0x7fffu + ((v.u >> 16) & 1u);
  return (unsigned short)(r >> 16);
}

// ---------------- prep kernels ----------------

__global__ void k_zero(int* counts, double* accum, int n){
  int i = blockIdx.x*blockDim.x + threadIdx.x;
  if (i < n) counts[i] = 0;
  if (i == 0) *accum = 0.0;
}

__global__ void k_hist(const int* __restrict__ idx, const int* __restrict__ lab,
                       int* __restrict__ counts, int n){
  int i = blockIdx.x*blockDim.x + threadIdx.x;
  if (i < n) atomicAdd(&counts[idx[i]*NCLS + lab[i]], 1);
}

// one block, M threads (M=1024). argmax labels + deterministic label-sorted permutation.
__global__ void k_label_perm(const int* __restrict__ counts, int* __restrict__ spLabel,
                             int* __restrict__ newpos, int* __restrict__ permLabel){
  int m = threadIdx.x;
  int best = 0; int bc = counts[m*NCLS];
  #pragma unroll
  for (int c = 1; c < NCLS; ++c){ int v = counts[m*NCLS+c]; if (v > bc){ bc = v; best = c; } }
  spLabel[m] = best;

  __shared__ int waveCnt[16][NCLS];
  __shared__ int waveOff[16][NCLS];
  __shared__ int classTot[NCLS];
  __shared__ int classBase[NCLS];
  int lane = m & 63, wid = m >> 6;
  int nw = blockDim.x >> 6;
  int rankInWave = 0;
  unsigned long long below = (1ull << lane) - 1ull;
  for (int c = 0; c < NCLS; ++c){
    unsigned long long bal = __ballot(best == c);
    if (best == c) rankInWave = __popcll(bal & below);
    if (lane == 0) waveCnt[wid][c] = __popcll(bal);
  }
  __syncthreads();
  if (m < NCLS){
    int c = m, s = 0;
    for (int w = 0; w < nw; ++w){ waveOff[w][c] = s; s += waveCnt[w][c]; }
    classTot[c] = s;
  }
  __syncthreads();
  if (m == 0){ int s = 0; for (int c = 0; c < NCLS; ++c){ classBase[c] = s; s += classTot[c]; } }
  __syncthreads();
  int pos = classBase[best] + waveOff[wid][best] + rankInWave;
  newpos[m] = pos;
  permLabel[pos] = best;
}

// one wave per superpoint row: normalize, write bf16 in original and permuted order
__global__ void k_norm_sp(const float* __restrict__ sp, const int* __restrict__ newpos,
                          unsigned short* __restrict__ spnO, unsigned short* __restrict__ spnP){
  int m = blockIdx.x, lane = threadIdx.x;
  const float4 v = *(const float4*)(sp + (size_t)m*DIM + lane*4);
  float ss = v.x*v.x + v.y*v.y + v.z*v.z + v.w*v.w;
  #pragma unroll
  for (int o = 1; o < 64; o <<= 1) ss += __shfl_xor(ss, o);
  float rn = 1.0f / sqrtf(ss + 1e-12f);
  uint2 w;
  w.x = (unsigned)f2bf(v.x*rn) | ((unsigned)f2bf(v.y*rn) << 16);
  w.y = (unsigned)f2bf(v.z*rn) | ((unsigned)f2bf(v.w*rn) << 16);
  *(uint2*)(spnO + (size_t)m*DIM + lane*4) = w;
  int p = newpos[m];
  *(uint2*)(spnP + (size_t)p*DIM + lane*4) = w;
}

// ---------------- main fused GEMM ----------------

__device__ __forceinline__ int swzA(int row, int k){ return (row*DIM + k) ^ ((row & 7) << 3); }

// LDS (67.6 KB) caps occupancy at 2 blocks/CU = 4 waves/EU; pin the register
// allocator to that (128 VGPR budget) so it doesn't spill chasing 8 waves/EU.
__attribute__((amdgpu_waves_per_eu(4, 4)))
__launch_bounds__(512)
__global__ void k_main(const float* __restrict__ rp, const int* __restrict__ rawIdx,
                       const unsigned short* __restrict__ spnO, const unsigned short* __restrict__ spnP,
                       const int* __restrict__ permLabel, const int* __restrict__ spLabel,
                       double* __restrict__ accum, int M){
  __shared__ __align__(16) unsigned short Ash[128*DIM];  // 64 KB, XOR-swizzled bf16
  __shared__ float posLogit[128];
  __shared__ int   posLab[128];
  __shared__ float negH[2][128];   // per-column-half neg sums, combined at the end

  const int tid  = threadIdx.x;
  const int lane = tid & 63, wid = tid >> 6;
  const int l15  = lane & 15, l4 = lane >> 4;
  const int rowBlock = blockIdx.x * 128;

  // stage A: normalize 128 rp rows -> bf16 LDS (one wave per 16 rows)
  for (int rr = 0; rr < 16; ++rr){
    int row = wid*16 + rr;
    const float4 v = *(const float4*)(rp + (size_t)(rowBlock + row)*DIM + lane*4);
    float ss = v.x*v.x + v.y*v.y + v.z*v.z + v.w*v.w;
    #pragma unroll
    for (int o = 1; o < 64; o <<= 1) ss += __shfl_xor(ss, o);
    float rn = 1.0f / sqrtf(ss + 1e-12f);
    uint2 w;
    w.x = (unsigned)f2bf(v.x*rn) | ((unsigned)f2bf(v.y*rn) << 16);
    w.y = (unsigned)f2bf(v.z*rn) | ((unsigned)f2bf(v.w*rn) << 16);
    *(uint2*)&Ash[swzA(row, lane*4)] = w;
  }
  __syncthreads();

  // positive logits: dot(rp_n[row], sp_n[idx_row]) via full-wave reduce
  for (int rr = 0; rr < 16; ++rr){
    int row  = wid*16 + rr;
    int sidx = rawIdx[rowBlock + row];
    uint2 av = *(const uint2*)&Ash[swzA(row, lane*4)];
    uint2 sv = *(const uint2*)(spnO + (size_t)sidx*DIM + lane*4);
    float d = bf2f(av.x & 0xffff)*bf2f(sv.x & 0xffff)
            + bf2f(av.x >> 16)  *bf2f(sv.x >> 16)
            + bf2f(av.y & 0xffff)*bf2f(sv.y & 0xffff)
            + bf2f(av.y >> 16)  *bf2f(sv.y >> 16);
    #pragma unroll
    for (int o = 1; o < 64; o <<= 1) d += __shfl_xor(d, o);
    if (lane == 0){ posLogit[row] = d; posLab[row] = spLabel[sidx]; }
  }
  __syncthreads();

  // GEMM: wave grid 4(rows) x 2(col-halves); per wave 32 rows x 64 cols per tile
  const int wr = wid >> 1, wc = wid & 1;
  float sumT[8] = {0,0,0,0,0,0,0,0}, sumO[8] = {0,0,0,0,0,0,0,0};
  int Lrow[8];
  #pragma unroll
  for (int rf = 0; rf < 2; ++rf)
    #pragma unroll
    for (int e = 0; e < 4; ++e)
      Lrow[rf*4+e] = posLab[wr*32 + rf*16 + l4*4 + e];

  const int nTiles = M / 128;
  for (int tb = 0; tb < nTiles; ++tb){
    const int colBase = tb*128 + wc*64;
    int labC[4];
    #pragma unroll
    for (int cf = 0; cf < 4; ++cf) labC[cf] = permLabel[colBase + cf*16 + l15];

    f32x4 acc[2][4];
    #pragma unroll
    for (int rf = 0; rf < 2; ++rf)
      #pragma unroll
      for (int cf = 0; cf < 4; ++cf) acc[rf][cf] = (f32x4){0.f,0.f,0.f,0.f};

    #pragma unroll
    for (int kf = 0; kf < 8; ++kf){
      const int k = kf*32 + l4*8;
      bf16x8 a0 = *(const bf16x8*)&Ash[swzA(wr*32 +      l15, k)];
      bf16x8 a1 = *(const bf16x8*)&Ash[swzA(wr*32 + 16 + l15, k)];
      #pragma unroll
      for (int cf = 0; cf < 4; ++cf){
        const int col = colBase + cf*16 + l15;
        bf16x8 b = *(const bf16x8*)(spnP + (size_t)col*DIM + k);
        acc[0][cf] = __builtin_amdgcn_mfma_f32_16x16x32_bf16(a0, b, acc[0][cf], 0, 0, 0);
        acc[1][cf] = __builtin_amdgcn_mfma_f32_16x16x32_bf16(a1, b, acc[1][cf], 0, 0, 0);
      }
    }

    // fused epilogue: exp + class-bucketed per-row partial sums (registers only)
    #pragma unroll
    for (int rf = 0; rf < 2; ++rf)
      #pragma unroll
      for (int cf = 0; cf < 4; ++cf)
        #pragma unroll
        for (int e = 0; e < 4; ++e){
          float ev = __expf(acc[rf][cf][e] * INV_T);
          int ri = rf*4 + e;
          sumT[ri] += ev;
          sumO[ri] += (labC[cf] == Lrow[ri]) ? ev : 0.0f;
        }
  }

  // cross-lane reduce over the 16 lanes holding the same rows (within l4 group)
  #pragma unroll
  for (int i = 0; i < 8; ++i){
    #pragma unroll
    for (int o = 1; o < 16; o <<= 1){
      sumT[i] += __shfl_xor(sumT[i], o);
      sumO[i] += __shfl_xor(sumO[i], o);
    }
  }

  // each wave owns HALF the columns of its 32 rows -> stage per-half neg, combine after sync
  if (l15 == 0){
    #pragma unroll
    for (int rf = 0; rf < 2; ++rf)
      #pragma unroll
      for (int e = 0; e < 4; ++e){
        int row = wr*32 + rf*16 + l4*4 + e;
        negH[wc][row] = sumT[rf*4+e] - sumO[rf*4+e];
      }
  }
  __syncthreads();

  if (tid < 64){  // wave 0: 2 rows per lane, combine halves, reduce, one atomic
    float part = 0.f;
    #pragma unroll
    for (int h = 0; h < 2; ++h){
      int row = tid*2 + h;
      float pl  = posLogit[row] * INV_T;
      float ep  = __expf(pl);
      float den = ep + negH[0][row] + negH[1][row] + 1e-8f;
      part += __logf(den) - pl;
    }
    #pragma unroll
    for (int o = 1; o < 64; o <<= 1) part += __shfl_xor(part, o);
    if (tid == 0) atomicAdd(accum, (double)part);
  }
}

__global__ void k_final(const double* __restrict__ accum, float* __restrict__ out, int N){
  out[0] = (float)((*accum / (double)N) * 0.07);
}

// ---------------- launch ----------------

extern "C" void kernel_launch(void* const* d_in, const int* in_sizes, int n_in,
                              void* d_out, int out_size, void* d_ws, size_t ws_size,
                              hipStream_t stream){
  const float* sp  = (const float*)d_in[0];
  const float* rp  = (const float*)d_in[1];
  const int*   idx = (const int*)d_in[2];
  const int*   lab = (const int*)d_in[3];
  const int M = in_sizes[0] / DIM;     // 1024
  const int N = in_sizes[2];           // 131072

  char* ws = (char*)d_ws;
  size_t off = 0;
  auto alloc = [&](size_t bytes){ void* p = ws + off; off = (off + bytes + 255) & ~(size_t)255; return p; };
  int*    counts    = (int*)   alloc((size_t)M * NCLS * 4);
  int*    spLabel   = (int*)   alloc((size_t)M * 4);
  int*    newpos    = (int*)   alloc((size_t)M * 4);
  int*    permLabel = (int*)   alloc((size_t)M * 4);
  double* accum     = (double*)alloc(16);
  unsigned short* spnO = (unsigned short*)alloc((size_t)M * DIM * 2);
  unsigned short* spnP = (unsigned short*)alloc((size_t)M * DIM * 2);

  k_zero<<<(M*NCLS + 255)/256, 256, 0, stream>>>(counts, accum, M*NCLS);
  k_hist<<<(N + 255)/256, 256, 0, stream>>>(idx, lab, counts, N);
  k_label_perm<<<1, M, 0, stream>>>(counts, spLabel, newpos, permLabel);
  k_norm_sp<<<M, 64, 0, stream>>>(sp, newpos, spnO, spnP);
  k_main<<<N/128, 512, 0, stream>>>(rp, idx, spnO, spnP, permLabel, spLabel, accum, M);
  k_final<<<1, 1, 0, stream>>>(accum, (float*)d_out, N);
}

// Round 4
// 216.744 us; speedup vs baseline: 1.5683x; 1.5683x over previous
//
#include <hip/hip_runtime.h>

#define NCLS 13
#define DIM  256
#define INV_T (1.0f/0.07f)

typedef short bf16x8 __attribute__((ext_vector_type(8)));
typedef float f32x4  __attribute__((ext_vector_type(4)));

__device__ __forceinline__ float bf2f(unsigned short u){
  union { unsigned u; float f; } v; v.u = ((unsigned)u) << 16; return v.f;
}
__device__ __forceinline__ unsigned short f2bf(float f){
  union { float f; unsigned u; } v; v.f = f;
  unsigned r = v.u + 0x7fffu + ((v.u >> 16) & 1u);
  return (unsigned short)(r >> 16);
}

__device__ __forceinline__ void gload_lds16(const void* g, void* l){
  __builtin_amdgcn_global_load_lds((const __attribute__((address_space(1))) unsigned*)g,
                                   (__attribute__((address_space(3))) unsigned*)l, 16, 0, 0);
}

// ---------------- prep kernels ----------------

__global__ void k_zero(int* counts, double* accum, int n){
  int i = blockIdx.x*blockDim.x + threadIdx.x;
  if (i < n) counts[i] = 0;
  if (i == 0) *accum = 0.0;
}

__global__ void k_hist(const int* __restrict__ idx, const int* __restrict__ lab,
                       int* __restrict__ counts, int n){
  int i = blockIdx.x*blockDim.x + threadIdx.x;
  if (i < n) atomicAdd(&counts[idx[i]*NCLS + lab[i]], 1);
}

// one block, M threads (M=1024). argmax labels + deterministic label-sorted permutation.
__global__ void k_label_perm(const int* __restrict__ counts, int* __restrict__ spLabel,
                             int* __restrict__ newpos, int* __restrict__ permLabel){
  int m = threadIdx.x;
  int best = 0; int bc = counts[m*NCLS];
  #pragma unroll
  for (int c = 1; c < NCLS; ++c){ int v = counts[m*NCLS+c]; if (v > bc){ bc = v; best = c; } }
  spLabel[m] = best;

  __shared__ int waveCnt[16][NCLS];
  __shared__ int waveOff[16][NCLS];
  __shared__ int classTot[NCLS];
  __shared__ int classBase[NCLS];
  int lane = m & 63, wid = m >> 6;
  int nw = blockDim.x >> 6;
  int rankInWave = 0;
  unsigned long long below = (1ull << lane) - 1ull;
  for (int c = 0; c < NCLS; ++c){
    unsigned long long bal = __ballot(best == c);
    if (best == c) rankInWave = __popcll(bal & below);
    if (lane == 0) waveCnt[wid][c] = __popcll(bal);
  }
  __syncthreads();
  if (m < NCLS){
    int c = m, s = 0;
    for (int w = 0; w < nw; ++w){ waveOff[w][c] = s; s += waveCnt[w][c]; }
    classTot[c] = s;
  }
  __syncthreads();
  if (m == 0){ int s = 0; for (int c = 0; c < NCLS; ++c){ classBase[c] = s; s += classTot[c]; } }
  __syncthreads();
  int pos = classBase[best] + waveOff[wid][best] + rankInWave;
  newpos[m] = pos;
  permLabel[pos] = best;
}

// one wave per superpoint row: normalize, write bf16 in original and permuted order
__global__ void k_norm_sp(const float* __restrict__ sp, const int* __restrict__ newpos,
                          unsigned short* __restrict__ spnO, unsigned short* __restrict__ spnP){
  int m = blockIdx.x, lane = threadIdx.x;
  const float4 v = *(const float4*)(sp + (size_t)m*DIM + lane*4);
  float ss = v.x*v.x + v.y*v.y + v.z*v.z + v.w*v.w;
  #pragma unroll
  for (int o = 1; o < 64; o <<= 1) ss += __shfl_xor(ss, o);
  float rn = 1.0f / sqrtf(ss + 1e-12f);
  uint2 w;
  w.x = (unsigned)f2bf(v.x*rn) | ((unsigned)f2bf(v.y*rn) << 16);
  w.y = (unsigned)f2bf(v.z*rn) | ((unsigned)f2bf(v.w*rn) << 16);
  *(uint2*)(spnO + (size_t)m*DIM + lane*4) = w;
  int p = newpos[m];
  *(uint2*)(spnP + (size_t)p*DIM + lane*4) = w;
}

// ---------------- main fused pipelined GEMM ----------------
// BM=64 rows/block, 256 threads (4 waves, 2x2 wave grid; wave tile 32r x 64c).
// A: 64x256 bf16 in LDS (swizzled), staged once with fused normalize.
// B: [128 cols][64 k] bf16 chunks, double-buffered, staged via global_load_lds
//    (linear LDS dest + inverse-swizzled global source; read with same swizzle).
// LDS = 32K(A) + 32K(B dbuf) + ~1K = 66.5 KB -> 2 blocks/CU.

__device__ __forceinline__ int swzA(int row, int k){ return (row*DIM + k) ^ ((row & 7) << 3); }
__device__ __forceinline__ int swzB(int col, int kk){ return (col*64 + kk) ^ ((col & 7) << 3); }

__device__ __forceinline__ void stageB(const unsigned short* __restrict__ spnP,
                                       unsigned short* BshBuf, int ct, int kc,
                                       int wid, int lane){
  #pragma unroll
  for (int i = 0; i < 4; ++i){
    const int offp = i*4096 + wid*1024 + lane*16;          // linear byte in 16KB chunk
    const int col  = offp >> 7;                            // 128 B per col-row (64 k * 2B)
    const int kkb  = (offp & 127) ^ ((col & 7) << 4);      // inverse swizzle on source
    const char* src = (const char*)spnP + ((size_t)(ct*128 + col))*(DIM*2) + kc*128 + kkb;
    char* dst = (char*)BshBuf + i*4096 + wid*1024;         // wave-uniform base
    gload_lds16(src, dst);
  }
}

__attribute__((amdgpu_waves_per_eu(2)))
__launch_bounds__(256)
__global__ void k_main(const float* __restrict__ rp, const int* __restrict__ rawIdx,
                       const unsigned short* __restrict__ spnO, const unsigned short* __restrict__ spnP,
                       const int* __restrict__ permLabel, const int* __restrict__ spLabel,
                       double* __restrict__ accum, int M){
  __shared__ __align__(16) unsigned short Ash[64*DIM];     // 32 KB
  __shared__ __align__(16) unsigned short Bsh[2][128*64];  // 32 KB double-buffered
  __shared__ float posLogit[64];
  __shared__ int   posLab[64];
  __shared__ float negH[2][64];

  const int tid  = threadIdx.x;
  const int lane = tid & 63, wid = tid >> 6;
  const int l15  = lane & 15, l4 = lane >> 4;
  const int rowBlock = blockIdx.x * 64;

  // issue chunk0 B-stage immediately (latency hides under A-normalize)
  stageB(spnP, &Bsh[0][0], 0, 0, wid, lane);

  // stage A: normalize 64 rp rows -> bf16 LDS (one wave per 16 rows)
  for (int rr = 0; rr < 16; ++rr){
    int row = wid*16 + rr;
    const float4 v = *(const float4*)(rp + (size_t)(rowBlock + row)*DIM + lane*4);
    float ss = v.x*v.x + v.y*v.y + v.z*v.z + v.w*v.w;
    #pragma unroll
    for (int o = 1; o < 64; o <<= 1) ss += __shfl_xor(ss, o);
    float rn = 1.0f / sqrtf(ss + 1e-12f);
    uint2 w;
    w.x = (unsigned)f2bf(v.x*rn) | ((unsigned)f2bf(v.y*rn) << 16);
    w.y = (unsigned)f2bf(v.z*rn) | ((unsigned)f2bf(v.w*rn) << 16);
    *(uint2*)&Ash[swzA(row, lane*4)] = w;
  }

  // positive logits (same-wave rows: no barrier needed before reading Ash)
  for (int rr = 0; rr < 16; ++rr){
    int row  = wid*16 + rr;
    int sidx = rawIdx[rowBlock + row];
    uint2 av = *(const uint2*)&Ash[swzA(row, lane*4)];
    uint2 sv = *(const uint2*)(spnO + (size_t)sidx*DIM + lane*4);
    float d = bf2f(av.x & 0xffff)*bf2f(sv.x & 0xffff)
            + bf2f(av.x >> 16)  *bf2f(sv.x >> 16)
            + bf2f(av.y & 0xffff)*bf2f(sv.y & 0xffff)
            + bf2f(av.y >> 16)  *bf2f(sv.y >> 16);
    #pragma unroll
    for (int o = 1; o < 64; o <<= 1) d += __shfl_xor(d, o);
    if (lane == 0){ posLogit[row] = d; posLab[row] = spLabel[sidx]; }
  }
  __syncthreads();   // A visible to all waves + chunk0 vmcnt drained

  const int wr = wid >> 1, wc = wid & 1;
  float sumT[8] = {0,0,0,0,0,0,0,0}, sumO[8] = {0,0,0,0,0,0,0,0};
  int Lrow[8];
  #pragma unroll
  for (int rf = 0; rf < 2; ++rf)
    #pragma unroll
    for (int e = 0; e < 4; ++e)
      Lrow[rf*4+e] = posLab[wr*32 + rf*16 + l4*4 + e];

  f32x4 acc[2][4];
  #pragma unroll
  for (int rf = 0; rf < 2; ++rf)
    #pragma unroll
    for (int cf = 0; cf < 4; ++cf) acc[rf][cf] = (f32x4){0.f,0.f,0.f,0.f};
  int labC[4];

  // 32 chunks: 8 col-tiles x 4 k-chunks; acc carries over kc, epilogue at kc==3
  for (int idx = 0; idx < 32; ++idx){
    const int ct = idx >> 2, kc = idx & 3, cur = idx & 1;
    if (idx + 1 < 32)
      stageB(spnP, &Bsh[cur^1][0], (idx+1) >> 2, (idx+1) & 3, wid, lane);  // prefetch next
    if (kc == 0){
      #pragma unroll
      for (int cf = 0; cf < 4; ++cf) labC[cf] = permLabel[ct*128 + wc*64 + cf*16 + l15];
    }
    #pragma unroll
    for (int kf = 0; kf < 2; ++kf){
      const int k  = kc*64 + kf*32 + l4*8;
      const int kb = kf*32 + l4*8;
      bf16x8 a0 = *(const bf16x8*)&Ash[swzA(wr*32 +      l15, k)];
      bf16x8 a1 = *(const bf16x8*)&Ash[swzA(wr*32 + 16 + l15, k)];
      #pragma unroll
      for (int cf = 0; cf < 4; ++cf){
        bf16x8 b = *(const bf16x8*)&Bsh[cur][swzB(wc*64 + cf*16 + l15, kb)];
        acc[0][cf] = __builtin_amdgcn_mfma_f32_16x16x32_bf16(a0, b, acc[0][cf], 0, 0, 0);
        acc[1][cf] = __builtin_amdgcn_mfma_f32_16x16x32_bf16(a1, b, acc[1][cf], 0, 0, 0);
      }
    }
    if (kc == 3){
      #pragma unroll
      for (int rf = 0; rf < 2; ++rf)
        #pragma unroll
        for (int cf = 0; cf < 4; ++cf){
          #pragma unroll
          for (int e = 0; e < 4; ++e){
            float ev = __expf(acc[rf][cf][e] * INV_T);
            int ri = rf*4 + e;
            sumT[ri] += ev;
            sumO[ri] += (labC[cf] == Lrow[ri]) ? ev : 0.0f;
          }
          acc[rf][cf] = (f32x4){0.f,0.f,0.f,0.f};
        }
    }
    __syncthreads();   // drains this iter's prefetch; next buffer safe+ready
  }

  // reduce over the 16 lanes sharing rows
  #pragma unroll
  for (int i = 0; i < 8; ++i){
    #pragma unroll
    for (int o = 1; o < 16; o <<= 1){
      sumT[i] += __shfl_xor(sumT[i], o);
      sumO[i] += __shfl_xor(sumO[i], o);
    }
  }

  if (l15 == 0){
    #pragma unroll
    for (int rf = 0; rf < 2; ++rf)
      #pragma unroll
      for (int e = 0; e < 4; ++e){
        int row = wr*32 + rf*16 + l4*4 + e;
        negH[wc][row] = sumT[rf*4+e] - sumO[rf*4+e];
      }
  }
  __syncthreads();

  if (tid < 64){   // wave 0: one row per lane
    int row = tid;
    float pl  = posLogit[row] * INV_T;
    float ep  = __expf(pl);
    float den = ep + negH[0][row] + negH[1][row] + 1e-8f;
    float part = __logf(den) - pl;
    #pragma unroll
    for (int o = 1; o < 64; o <<= 1) part += __shfl_xor(part, o);
    if (tid == 0) atomicAdd(accum, (double)part);
  }
}

__global__ void k_final(const double* __restrict__ accum, float* __restrict__ out, int N){
  out[0] = (float)((*accum / (double)N) * 0.07);
}

// ---------------- launch ----------------

extern "C" void kernel_launch(void* const* d_in, const int* in_sizes, int n_in,
                              void* d_out, int out_size, void* d_ws, size_t ws_size,
                              hipStream_t stream){
  const float* sp  = (const float*)d_in[0];
  const float* rp  = (const float*)d_in[1];
  const int*   idx = (const int*)d_in[2];
  const int*   lab = (const int*)d_in[3];
  const int M = in_sizes[0] / DIM;     // 1024
  const int N = in_sizes[2];           // 131072

  char* ws = (char*)d_ws;
  size_t off = 0;
  auto alloc = [&](size_t bytes){ void* p = ws + off; off = (off + bytes + 255) & ~(size_t)255; return p; };
  int*    counts    = (int*)   alloc((size_t)M * NCLS * 4);
  int*    spLabel   = (int*)   alloc((size_t)M * 4);
  int*    newpos    = (int*)   alloc((size_t)M * 4);
  int*    permLabel = (int*)   alloc((size_t)M * 4);
  double* accum     = (double*)alloc(16);
  unsigned short* spnO = (unsigned short*)alloc((size_t)M * DIM * 2);
  unsigned short* spnP = (unsigned short*)alloc((size_t)M * DIM * 2);

  k_zero<<<(M*NCLS + 255)/256, 256, 0, stream>>>(counts, accum, M*NCLS);
  k_hist<<<(N + 255)/256, 256, 0, stream>>>(idx, lab, counts, N);
  k_label_perm<<<1, M, 0, stream>>>(counts, spLabel, newpos, permLabel);
  k_norm_sp<<<M, 64, 0, stream>>>(sp, newpos, spnO, spnP);
  k_main<<<N/64, 256, 0, stream>>>(rp, idx, spnO, spnP, permLabel, spLabel, accum, M);
  k_final<<<1, 1, 0, stream>>>(accum, (float*)d_out, N);
}